// Round 1
// baseline (409.007 us; speedup 1.0000x reference)
//
#include <hip/hip_runtime.h>
#include <math.h>

// Fixed problem shapes (AdaptiveGraphDeformation_45990509806147)
#define Bn   16
#define Hn   128
#define Wn   128
#define Cn   192
#define HPn  64
#define WPn  64
#define LPn  4096    // HPn*WPn
#define Ln   16384   // Hn*Wn
#define HIDn 64

__device__ __forceinline__ float gelu_exact(float x) {
    return 0.5f * x * (1.0f + erff(x * 0.70710678118654752440f));
}
__device__ __forceinline__ float softplus_f(float x) {
    // matches jax.nn.softplus = logaddexp(x, 0)
    return fmaxf(x, 0.0f) + log1pf(expf(-fabsf(x)));
}

// Kernel 1: 2x2 avg-pool + 2-layer MLP + activations + deformed coords.
// One block handles 16 consecutive pooled positions (same b, same hp row).
__global__ __launch_bounds__(256)
void pool_mlp_kernel(const float* __restrict__ feat,
                     const float* __restrict__ W1,
                     const float* __restrict__ b1,
                     const float* __restrict__ W2,
                     const float* __restrict__ b2,
                     const float* __restrict__ wcoef,
                     float* __restrict__ out_params,   // (B, LP, 4)
                     float* __restrict__ out_coords)   // (B, LP, 2)
{
    __shared__ float s_pool[16][Cn];
    __shared__ float s_hid[16][HIDn];
    const int t = threadIdx.x;
    const int g0  = blockIdx.x * 16;   // first pooled-position index
    const int b   = g0 >> 12;          // / 4096
    const int lp0 = g0 & 4095;
    const int hp  = lp0 >> 6;
    const int wp0 = lp0 & 63;

    const float* fb = feat + (size_t)b * Ln * Cn;
    const int h0 = hp * 2;

    // ---- pooling: 16 positions x 192 channels = 3072 values, 12 per thread
#pragma unroll
    for (int k = 0; k < 12; ++k) {
        int v = t + k * 256;
        int p = v / Cn;
        int c = v - p * Cn;
        int w0 = (wp0 + p) * 2;
        size_t base = ((size_t)h0 * Wn + w0) * Cn + c;
        float s = fb[base] + fb[base + Cn] + fb[base + (size_t)Wn * Cn] +
                  fb[base + (size_t)Wn * Cn + Cn];
        s_pool[p][c] = 0.25f * s;
    }
    __syncthreads();

    // ---- hidden layer: thread t computes hidden j = t&63 for 4 positions
    const int j  = t & 63;
    const int pb = t >> 6;
    float a0 = b1[j], a1 = a0, a2 = a0, a3 = a0;
    for (int c = 0; c < Cn; ++c) {
        float w = W1[c * HIDn + j];        // coalesced across the wave
        a0 = fmaf(s_pool[pb     ][c], w, a0);   // LDS broadcast reads
        a1 = fmaf(s_pool[pb +  4][c], w, a1);
        a2 = fmaf(s_pool[pb +  8][c], w, a2);
        a3 = fmaf(s_pool[pb + 12][c], w, a3);
    }
    s_hid[pb     ][j] = gelu_exact(a0);
    s_hid[pb +  4][j] = gelu_exact(a1);
    s_hid[pb +  8][j] = gelu_exact(a2);
    s_hid[pb + 12][j] = gelu_exact(a3);
    __syncthreads();

    // ---- output layer: 16 positions x 4 outputs = 64 values
    if (t < 64) {
        int p = t >> 2, k = t & 3;
        float acc = b2[k];
        for (int c = 0; c < HIDn; ++c)
            acc = fmaf(s_hid[p][c], W2[c * 4 + k], acc);
        float dp = acc * wcoef[k];
        float val = (k < 2) ? tanhf(dp) : softplus_f(dp);
        int lp = lp0 + p;
        out_params[((size_t)b * LPn + lp) * 4 + k] = val;
        if (k == 0) {
            float ox = 2.0f * (float)(wp0 + p) / 63.0f - 1.0f;
            float dx = ox + val * (2.0f / 64.0f);
            dx = fminf(fmaxf(dx, -1.0f), 1.0f);
            out_coords[((size_t)b * LPn + lp) * 2 + 0] = dx;
        } else if (k == 1) {
            float oy = 2.0f * (float)hp / 63.0f - 1.0f;
            float dy = oy + val * (2.0f / 64.0f);
            dy = fminf(fmaxf(dy, -1.0f), 1.0f);
            out_coords[((size_t)b * LPn + lp) * 2 + 1] = dy;
        }
    }
}

// Kernel 2: bilinear-upsample coords (64->128, align_corners=True) +
// grid_sample (bilinear, border, align_corners=True).
// One thread per (pixel, c4) float4 of the output.
__global__ __launch_bounds__(256)
void sample_kernel(const float* __restrict__ feat,
                   const float* __restrict__ coords,  // (B, LP, 2)
                   float* __restrict__ out)           // (B, L, C)
{
    const int idx = blockIdx.x * 256 + threadIdx.x;   // < B*H*W*48
    const int pix = idx / 48;
    const int c4  = idx - pix * 48;
    const int b   = pix >> 14;          // / (H*W)
    const int rem = pix & 16383;
    const int i   = rem >> 7;           // output row
    const int jj  = rem & 127;          // output col

    // ---- upsample deformed_coords to full res (align_corners=True)
    const float sc = 63.0f / 127.0f;
    float py = i * sc, px = jj * sc;
    float fy0 = floorf(py), fx0 = floorf(px);
    float wy = py - fy0, wx = px - fx0;
    int iy0 = (int)fy0, ix0 = (int)fx0;
    int iy1 = min(iy0 + 1, 63), ix1 = min(ix0 + 1, 63);
    const float2* cm = (const float2*)coords + ((size_t)b << 12);
    float2 c00 = cm[iy0 * 64 + ix0];
    float2 c01 = cm[iy0 * 64 + ix1];
    float2 c10 = cm[iy1 * 64 + ix0];
    float2 c11 = cm[iy1 * 64 + ix1];
    float gx = (c00.x * (1.0f - wy) + c10.x * wy) * (1.0f - wx) +
               (c01.x * (1.0f - wy) + c11.x * wy) * wx;
    float gy = (c00.y * (1.0f - wy) + c10.y * wy) * (1.0f - wx) +
               (c01.y * (1.0f - wy) + c11.y * wy) * wx;

    // ---- grid sample mapping
    float ix = (gx + 1.0f) * 0.5f * 127.0f;
    float iy = (gy + 1.0f) * 0.5f * 127.0f;
    ix = fminf(fmaxf(ix, 0.0f), 127.0f);
    iy = fminf(fmaxf(iy, 0.0f), 127.0f);
    float fx = floorf(ix), fy = floorf(iy);
    float swx = ix - fx, swy = iy - fy;
    int sx0 = (int)fx, sy0 = (int)fy;
    int sx1 = min(sx0 + 1, 127), sy1 = min(sy0 + 1, 127);

    const float4* f4 = (const float4*)feat + ((size_t)b << 14) * 48;
    float4 v00 = f4[(sy0 * 128 + sx0) * 48 + c4];
    float4 v01 = f4[(sy0 * 128 + sx1) * 48 + c4];
    float4 v10 = f4[(sy1 * 128 + sx0) * 48 + c4];
    float4 v11 = f4[(sy1 * 128 + sx1) * 48 + c4];

    float iwx = 1.0f - swx, iwy = 1.0f - swy;
    float4 r;
    r.x = (v00.x * iwx + v01.x * swx) * iwy + (v10.x * iwx + v11.x * swx) * swy;
    r.y = (v00.y * iwx + v01.y * swx) * iwy + (v10.y * iwx + v11.y * swx) * swy;
    r.z = (v00.z * iwx + v01.z * swx) * iwy + (v10.z * iwx + v11.z * swx) * swy;
    r.w = (v00.w * iwx + v01.w * swx) * iwy + (v10.w * iwx + v11.w * swx) * swy;
    ((float4*)out)[idx] = r;
}

extern "C" void kernel_launch(void* const* d_in, const int* in_sizes, int n_in,
                              void* d_out, int out_size, void* d_ws, size_t ws_size,
                              hipStream_t stream) {
    const float* feat = (const float*)d_in[0];
    // d_in[1]=H, d_in[2]=W (scalars; shapes are hard-coded)
    const float* W1 = (const float*)d_in[3];
    const float* b1 = (const float*)d_in[4];
    const float* W2 = (const float*)d_in[5];
    const float* b2 = (const float*)d_in[6];
    const float* wc = (const float*)d_in[7];

    float* out        = (float*)d_out;
    float* out_params = out + (size_t)Bn * Ln * Cn;            // 50331648
    float* out_coords = out_params + (size_t)Bn * LPn * 4;     // +262144

    // 65536 pooled positions / 16 per block
    pool_mlp_kernel<<<(Bn * LPn) / 16, 256, 0, stream>>>(
        feat, W1, b1, W2, b2, wc, out_params, out_coords);

    // B*H*W*48 float4 outputs, 256 threads/block -> 49152 blocks exactly
    sample_kernel<<<(Bn * Hn * Wn * 48) / 256, 256, 0, stream>>>(
        feat, out_coords, out);
}